// Round 3
// baseline (23757.059 us; speedup 1.0000x reference)
//
#include <hip/hip_runtime.h>

// ---------------------------------------------------------------------------
// Seq2SeqAttentionDecoder — round 3
//  * big GEMMs (keys, gi0x, logits): round-1 fp32 k_gemm_tiled (PROVEN path;
//    round-2 MFMA swap regressed 3 ms unexplained -> reverted, re-isolate later)
//  * entire 64-step recurrence: ONE persistent kernel, 256 blocks x 256 thr
//    (co-resident by capacity), software grid barrier (agent-scope atomics),
//    5 phases/step: q -> scores -> softmax+ctx -> GRU-L0 -> GRU-L1
//  * recurrent weights (Wq, Wih0[:, :H], Whh0, Wih1, Whh1) pre-converted bf16
//  * outs[t] doubles as h1 storage (no copy); h0 double-buffered by parity
//  * 12 dispatches total (was ~460) -> should also unblock rocprof parsing
// ---------------------------------------------------------------------------

#define BB 32
#define TT 64
#define SS 128
#define HH 1024
#define EE 512
#define VV 32000
#define H3 3072
#define NEGV (-1000000.0f)
#define NB 256          // persistent grid blocks

typedef __attribute__((ext_vector_type(8))) unsigned short u16x8;

__device__ __forceinline__ unsigned short f2bf(float f) {
  unsigned int u = __builtin_bit_cast(unsigned int, f);
  unsigned int r = (u + 0x7FFFu + ((u >> 16) & 1u)) >> 16;   // RNE
  return (unsigned short)r;
}
__device__ __forceinline__ float bfu(unsigned short u) {
  return __builtin_bit_cast(float, (unsigned int)u << 16);
}
__device__ __forceinline__ float sigm(float x) {
  return 1.f / (1.f + __expf(-x));
}
__device__ __forceinline__ float tanhfast(float x) {
  float ax = fabsf(x);
  float e = __expf(2.f * ax);
  float th = 1.f - 2.f / (e + 1.f);
  return copysignf(th, x);
}
__device__ __forceinline__ void fma8(float& acc, u16x8 w, float4 x0, float4 x1) {
  acc = fmaf(bfu(w[0]), x0.x, acc); acc = fmaf(bfu(w[1]), x0.y, acc);
  acc = fmaf(bfu(w[2]), x0.z, acc); acc = fmaf(bfu(w[3]), x0.w, acc);
  acc = fmaf(bfu(w[4]), x1.x, acc); acc = fmaf(bfu(w[5]), x1.y, acc);
  acc = fmaf(bfu(w[6]), x1.z, acc); acc = fmaf(bfu(w[7]), x1.w, acc);
}

// ---------- init: h0A = hidden[0], zero barrier counter ----------
__global__ __launch_bounds__(256) void k_init(const float* __restrict__ hid,
                                              float* __restrict__ h0A,
                                              unsigned* __restrict__ bar) {
  int i = blockIdx.x * 256 + threadIdx.x;
  if (i < BB * HH) h0A[i] = hid[i];
  if (i == 0) *bar = 0u;
}

// ---------- gather xs[r=t*B+b][e] = emb[X[b][t]][e]  (fp32, round-1) ----------
__global__ __launch_bounds__(256) void k_gather(const int* __restrict__ X,
                                                const float* __restrict__ emb,
                                                float* __restrict__ xs) {
  int idx = blockIdx.x * 256 + threadIdx.x;
  int r = idx >> 7, c4 = (idx & 127) << 2;
  int td = r >> 5, b = r & 31;
  int tok = X[b * TT + td];
  *(float4*)(xs + (size_t)r * EE + c4) =
      *(const float4*)(emb + (size_t)tok * EE + c4);
}

// ---------- fp32 -> packed bf16, generic ld / cols (grid = rows) ----------
__global__ __launch_bounds__(256) void k_conv(const float* __restrict__ src,
                                              unsigned short* __restrict__ dst,
                                              int cols4, int ld) {
  int r = blockIdx.x;
  for (int c = threadIdx.x; c < cols4; c += 256) {
    float4 v = *(const float4*)(src + (size_t)r * ld + (size_t)c * 4);
    ushort4 o;
    o.x = f2bf(v.x); o.y = f2bf(v.y); o.z = f2bf(v.z); o.w = f2bf(v.w);
    *(ushort4*)(dst + (size_t)r * cols4 * 4 + (size_t)c * 4) = o;
  }
}

// ---------- fp32 tiled GEMM (round-1, proven): C = A @ W^T (+bias) ----------
__global__ __launch_bounds__(256) void k_gemm_tiled(
    const float* __restrict__ A, int lda,
    const float* __restrict__ W, int ldw,
    const float* __restrict__ bias,
    float* __restrict__ C, int M, int N, int K, int permuteBT) {
  __shared__ float As[16][132];
  __shared__ float Ws[16][132];
  const int m0 = blockIdx.y * 128, n0 = blockIdx.x * 128;
  const int t = threadIdx.x;
  const int tm = t >> 4, tn = t & 15;
  float acc[8][8] = {};
  for (int k0 = 0; k0 < K; k0 += 16) {
#pragma unroll
    for (int qq = 0; qq < 2; ++qq) {
      int f = t * 2 + qq;
      int row = f >> 2, c4 = (f & 3) << 2;
      float4 va = *(const float4*)(A + (size_t)(m0 + row) * lda + k0 + c4);
      As[c4 + 0][row] = va.x; As[c4 + 1][row] = va.y;
      As[c4 + 2][row] = va.z; As[c4 + 3][row] = va.w;
      float4 vw = *(const float4*)(W + (size_t)(n0 + row) * ldw + k0 + c4);
      Ws[c4 + 0][row] = vw.x; Ws[c4 + 1][row] = vw.y;
      Ws[c4 + 2][row] = vw.z; Ws[c4 + 3][row] = vw.w;
    }
    __syncthreads();
#pragma unroll
    for (int k = 0; k < 16; ++k) {
      float a[8], w[8];
      *(float4*)&a[0] = *(const float4*)&As[k][tm * 8];
      *(float4*)&a[4] = *(const float4*)&As[k][tm * 8 + 4];
      *(float4*)&w[0] = *(const float4*)&Ws[k][tn * 8];
      *(float4*)&w[4] = *(const float4*)&Ws[k][tn * 8 + 4];
#pragma unroll
      for (int i = 0; i < 8; ++i)
#pragma unroll
        for (int j = 0; j < 8; ++j) acc[i][j] = fmaf(a[i], w[j], acc[i][j]);
    }
    __syncthreads();
  }
#pragma unroll
  for (int i = 0; i < 8; ++i) {
    int m = m0 + tm * 8 + i;
    size_t rowoff = permuteBT ? ((size_t)((m & 31) * TT + (m >> 5))) * N
                              : (size_t)m * N;
#pragma unroll
    for (int jj = 0; jj < 2; ++jj) {
      int n = n0 + tn * 8 + jj * 4;
      float4 v;
      v.x = acc[i][jj * 4 + 0]; v.y = acc[i][jj * 4 + 1];
      v.z = acc[i][jj * 4 + 2]; v.w = acc[i][jj * 4 + 3];
      if (bias) { v.x += bias[n]; v.y += bias[n + 1];
                  v.z += bias[n + 2]; v.w += bias[n + 3]; }
      *(float4*)(C + rowoff + n) = v;
    }
  }
}

// ---------- gates + GRU for one layer (pair of threads per output) ----------
// A: ih-side input [B][H] fp32; Hp: hh-side input (= h_prev) [B][H] fp32.
// wi/wh: packed bf16 [3H][H] (gate-major rows). gixrow: bf16 [B][3H] (or null,
// precomputed x-gates incl. b_ih). bih: fp32 [3H] or null. bhh: fp32 [3H].
// hdst[b][n] = GRU(...). Called by all 65536 threads (2 per output).
__device__ __forceinline__ void gates_gru(
    int gid, const float* __restrict__ A, const float* __restrict__ Hp,
    const unsigned short* __restrict__ wi, const unsigned short* __restrict__ wh,
    const unsigned short* __restrict__ gixrow, const float* __restrict__ bih,
    const float* __restrict__ bhh, float* __restrict__ hdst) {
  const int o = gid >> 1, half = gid & 1;
  const int b = o >> 10, n = o & 1023;
  const float* ar = A  + b * HH + half * 512;
  const float* hr = Hp + b * HH + half * 512;
  const size_t w0 = (size_t)n * HH + half * 512;
  float air = 0, aiz = 0, ain = 0, ahr = 0, ahz = 0, ahn = 0;
#pragma unroll 2
  for (int j = 0; j < 64; ++j) {
    float4 a0 = *(const float4*)(ar + j * 8);
    float4 a1 = *(const float4*)(ar + j * 8 + 4);
    float4 b0 = *(const float4*)(hr + j * 8);
    float4 b1 = *(const float4*)(hr + j * 8 + 4);
    fma8(air, *(const u16x8*)(wi + w0 + (size_t)j * 8),               a0, a1);
    fma8(aiz, *(const u16x8*)(wi + w0 + 1048576 + (size_t)j * 8),     a0, a1);
    fma8(ain, *(const u16x8*)(wi + w0 + 2097152 + (size_t)j * 8),     a0, a1);
    fma8(ahr, *(const u16x8*)(wh + w0 + (size_t)j * 8),               b0, b1);
    fma8(ahz, *(const u16x8*)(wh + w0 + 1048576 + (size_t)j * 8),     b0, b1);
    fma8(ahn, *(const u16x8*)(wh + w0 + 2097152 + (size_t)j * 8),     b0, b1);
  }
  air += __shfl_xor(air, 1); aiz += __shfl_xor(aiz, 1); ain += __shfl_xor(ain, 1);
  ahr += __shfl_xor(ahr, 1); ahz += __shfl_xor(ahz, 1); ahn += __shfl_xor(ahn, 1);
  if (half == 0) {
    float gr = air, gz = aiz, gn = ain;
    if (gixrow) {
      gr += bfu(gixrow[b * H3 + n]);
      gz += bfu(gixrow[b * H3 + HH + n]);
      gn += bfu(gixrow[b * H3 + 2 * HH + n]);
    }
    if (bih) { gr += bih[n]; gz += bih[HH + n]; gn += bih[2 * HH + n]; }
    float hrr = ahr + bhh[n], hz = ahz + bhh[HH + n], hn = ahn + bhh[2 * HH + n];
    float r = sigm(gr + hrr);
    float z = sigm(gz + hz);
    float nn = tanhfast(gn + r * hn);
    hdst[b * HH + n] = (1.f - z) * nn + z * Hp[b * HH + n];
  }
}

// ---------- the persistent recurrence kernel ----------
__global__ __launch_bounds__(256) void k_persist(
    const float* __restrict__ keys, const unsigned short* __restrict__ gi0xb,
    const unsigned short* __restrict__ wq,
    const unsigned short* __restrict__ wi0, const unsigned short* __restrict__ wh0,
    const unsigned short* __restrict__ wi1, const unsigned short* __restrict__ wh1,
    const float* __restrict__ enc, const float* __restrict__ wv,
    const int* __restrict__ vlen, const float* __restrict__ hid1,
    const float* __restrict__ bhh0, const float* __restrict__ bih1,
    const float* __restrict__ bhh1,
    float* __restrict__ q, float* __restrict__ scores, float* __restrict__ ctx,
    float* __restrict__ h0A, float* __restrict__ h0B, float* __restrict__ outs,
    unsigned* __restrict__ bar) {
  __shared__ float shm[1024];
  const int bid = blockIdx.x, t = threadIdx.x;
  const int gid = bid * 256 + t;
  unsigned ep = 0;

#define GBAR() do { ++ep; __syncthreads();                                     \
    if (t == 0) {                                                              \
      __threadfence();                                                         \
      __hip_atomic_fetch_add(bar, 1u, __ATOMIC_RELAXED,                        \
                             __HIP_MEMORY_SCOPE_AGENT);                        \
      while (__hip_atomic_load(bar, __ATOMIC_RELAXED,                          \
                               __HIP_MEMORY_SCOPE_AGENT) < ep * (unsigned)NB)  \
        __builtin_amdgcn_s_sleep(1);                                           \
      __threadfence();                                                         \
    }                                                                          \
    __syncthreads(); } while (0)

  for (int td = 0; td < TT; ++td) {
    const float* h1old = td ? outs + (size_t)(td - 1) * BB * HH : hid1;
    const float* h0old = (td & 1) ? h0B : h0A;
    float*       h0new = (td & 1) ? h0A : h0B;

    // ---- P1: q = h1 @ Wq^T  (2 threads per output, split K) ----
    {
      const int o = gid >> 1, half = gid & 1;
      const int b = o >> 10, n = o & 1023;
      const float* hrow = h1old + b * HH + half * 512;
      const unsigned short* wrow = wq + (size_t)n * HH + half * 512;
      float acc = 0;
#pragma unroll 4
      for (int j = 0; j < 64; ++j) {
        float4 a0 = *(const float4*)(hrow + j * 8);
        float4 a1 = *(const float4*)(hrow + j * 8 + 4);
        fma8(acc, *(const u16x8*)(wrow + (size_t)j * 8), a0, a1);
      }
      acc += __shfl_xor(acc, 1);
      if (half == 0) q[o] = acc;
    }
    GBAR();

    // ---- P2: scores[b][s] = sum_h tanh(q+keys)*wv, masked ----
    {
      const int b = bid >> 3, sg = bid & 7;
      *(float4*)&shm[t * 4] = *(const float4*)(q + b * HH + t * 4);
      __syncthreads();
      const int s = sg * 16 + (t >> 4), g = t & 15;
      const float* krow = keys + ((size_t)b * SS + s) * HH;
      float acc = 0;
#pragma unroll 4
      for (int j = 0; j < 64; ++j) {
        int h = g + j * 16;
        acc = fmaf(tanhfast(shm[h] + krow[h]), wv[h], acc);
      }
      acc += __shfl_xor(acc, 1); acc += __shfl_xor(acc, 2);
      acc += __shfl_xor(acc, 4); acc += __shfl_xor(acc, 8);
      if (g == 0) scores[b * SS + s] = (s < vlen[b]) ? acc : NEGV;
    }
    GBAR();

    // ---- P3: softmax + ctx = attn @ enc ----
    {
      const int b = bid >> 3, hc = bid & 7;
      if (t < SS) shm[t] = scores[b * SS + t];
      __syncthreads();
      float mx = shm[0];
#pragma unroll 8
      for (int s = 1; s < SS; ++s) mx = fmaxf(mx, shm[s]);
      float p = (t < SS) ? __expf(shm[t] - mx) : 0.f;
      __syncthreads();
      if (t < SS) shm[t] = p;
      __syncthreads();
      float sum = 0;
#pragma unroll 8
      for (int s = 0; s < SS; ++s) sum += shm[s];
      const float inv = 1.f / sum;
      const int c = hc * 128 + (t & 127), sh = t >> 7;
      float a = 0;
      const float* ep2 = enc + (size_t)b * SS * HH + c;
#pragma unroll 4
      for (int s = sh * 64; s < sh * 64 + 64; ++s)
        a = fmaf(shm[s], ep2[(size_t)s * HH], a);
      shm[512 + t] = a;
      __syncthreads();
      if (t < 128)
        ctx[b * HH + c] = (shm[512 + t] + shm[512 + 128 + t]) * inv;
    }
    GBAR();

    // ---- P4: layer-0 gates + GRU -> h0new ----
    gates_gru(gid, ctx, h0old, wi0, wh0,
              gi0xb + (size_t)td * BB * H3, nullptr, bhh0, h0new);
    GBAR();

    // ---- P5: layer-1 gates + GRU -> outs[td] (doubles as h1) ----
    gates_gru(gid, h0new, h1old, wi1, wh1,
              nullptr, bih1, bhh1, outs + (size_t)td * BB * HH);
    GBAR();
  }
#undef GBAR
}

// ---------------------------------------------------------------------------
extern "C" void kernel_launch(void* const* d_in, const int* in_sizes, int n_in,
                              void* d_out, int out_size, void* d_ws,
                              size_t ws_size, hipStream_t stream) {
  const int*   X    = (const int*)  d_in[0];
  const float* enc  = (const float*)d_in[1];
  const float* hid  = (const float*)d_in[2];
  const int*   vlen = (const int*)  d_in[3];
  const float* emb  = (const float*)d_in[4];
  const float* Wq   = (const float*)d_in[5];
  const float* Wk   = (const float*)d_in[6];
  const float* wv   = (const float*)d_in[7];
  const float* Wih0 = (const float*)d_in[8];
  const float* Whh0 = (const float*)d_in[9];
  const float* bih0 = (const float*)d_in[10];
  const float* bhh0 = (const float*)d_in[11];
  const float* Wih1 = (const float*)d_in[12];
  const float* Whh1 = (const float*)d_in[13];
  const float* bih1 = (const float*)d_in[14];
  const float* bhh1 = (const float*)d_in[15];
  const float* Wout = (const float*)d_in[16];
  const float* bout = (const float*)d_in[17];
  float* out = (float*)d_out;

  // ---- workspace layout (float offsets), total ~16.92M floats = 67.7 MB ----
  float* ws = (float*)d_ws;
  float*          keys   = ws;                                   // 4,194,304
  unsigned short* gi0xb  = (unsigned short*)(ws + 4194304);      // 3,145,728 f
  float*          outs   = ws + 7340032;                         // 2,097,152
  float*          xs     = ws + 9437184;                         // 1,048,576 (dead after gi0x GEMM)
  unsigned short* wqb    = (unsigned short*)xs;                  //   524,288 f (aliases xs)
  float*          h0A    = ws + 10485760;                        //    32,768
  float*          h0B    = ws + 10518528;                        //    32,768
  float*          q      = ws + 10551296;                        //    32,768
  float*          ctx    = ws + 10584064;                        //    32,768
  float*          scores = ws + 10616832;                        //     4,096
  unsigned*       bar    = (unsigned*)(ws + 10620928);           //        32 f pad
  float*          Wg     = ws + 10620960;                        // 6,291,456
  // Wg: first gi0x fp32 [2048x3072], then (after conv) 4 bf16 weight blocks
  float*          gi0xf  = Wg;
  unsigned short* wi0    = (unsigned short*)Wg;                  // [3072][1024]
  unsigned short* wh0    = wi0 + (size_t)3145728;
  unsigned short* wi1    = wh0 + (size_t)3145728;
  unsigned short* wh1    = wi1 + (size_t)3145728;

  k_init<<<128, 256, 0, stream>>>(hid, h0A, bar);
  k_gather<<<1024, 256, 0, stream>>>(X, emb, xs);
  // keys = enc @ Wk^T   (fp32)
  k_gemm_tiled<<<dim3(8, 32), 256, 0, stream>>>(enc, HH, Wk, HH, nullptr,
                                                keys, BB * SS, HH, HH, 0);
  // gi0xf = xs @ W_ih0[:,H:]^T + b_ih0   (fp32, into Wg region)
  k_gemm_tiled<<<dim3(24, 16), 256, 0, stream>>>(xs, EE, Wih0 + HH, HH + EE,
                                                 bih0, gi0xf, TT * BB, H3, EE, 0);
  // gi0xf -> bf16 (before Wg is overwritten by weights)
  k_conv<<<2048, 256, 0, stream>>>(gi0xf, gi0xb, 768, H3);
  // weights -> bf16 (wqb into dead xs region; gates into Wg)
  k_conv<<<1024, 256, 0, stream>>>(Wq, wqb, 256, HH);
  k_conv<<<3072, 256, 0, stream>>>(Wih0, wi0, 256, HH + EE);   // ctx cols only
  k_conv<<<3072, 256, 0, stream>>>(Whh0, wh0, 256, HH);
  k_conv<<<3072, 256, 0, stream>>>(Wih1, wi1, 256, HH);
  k_conv<<<3072, 256, 0, stream>>>(Whh1, wh1, 256, HH);

  // the whole 64-step recurrence in one launch
  k_persist<<<NB, 256, 0, stream>>>(keys, gi0xb, wqb, wi0, wh0, wi1, wh1,
                                    enc, wv, vlen, hid + BB * HH,
                                    bhh0, bih1, bhh1,
                                    q, scores, ctx, h0A, h0B, outs, bar);

  // logits = outs @ W_out^T + b_out  (fp32, permuted [t*B+b] -> [b,t])
  k_gemm_tiled<<<dim3(250, 16), 256, 0, stream>>>(outs, HH, Wout, HH, bout,
                                                  out, TT * BB, VV, HH, 1);
}